// Round 1
// baseline (204.372 us; speedup 1.0000x reference)
//
#include <hip/hip_runtime.h>

// Problem constants (match reference.py)
#define P_IDS 50000

// ---------------------------------------------------------------------------
// Kernel 1: per-hit scatter into per-particle num/den bins.
//   num[p] += mse_i * xi_i ; den[p] += xi_i   for valid hits with pid p != 0
// pred/track_params are [N,4] row-major -> one float4 per hit, coalesced.
// ---------------------------------------------------------------------------
__global__ void __launch_bounds__(256)
scatter_kernel(const float* __restrict__ beta,
               const float4* __restrict__ pred,
               const int* __restrict__ pid,
               const float4* __restrict__ track,
               const int* __restrict__ recon,
               float* __restrict__ num,
               float* __restrict__ den,
               int n) {
    int i = blockIdx.x * blockDim.x + threadIdx.x;
    if (i >= n) return;

    int p = pid[i];
    int r = recon[i];
    // Invalid hits and pid==0 noise go to segment 0 in the reference, which
    // is dropped -> skip the work (and the pred/track/beta loads) entirely.
    if (r <= 0 || p <= 0) return;

    float b = beta[i];
    float4 pr = pred[i];
    float4 tp = track[i];
    float dx = pr.x - tp.x;
    float dy = pr.y - tp.y;
    float dz = pr.z - tp.z;
    float dw = pr.w - tp.w;
    float mse = dx * dx + dy * dy + dz * dz + dw * dw;

    // arctanh(b) = 0.5 * log((1+b)/(1-b)); b in (0.01, 0.99) so finite.
    float at = 0.5f * logf((1.0f + b) / (1.0f - b));
    float xi = at * at;

    atomicAdd(&den[p], xi);
    atomicAdd(&num[p], mse * xi);
}

// ---------------------------------------------------------------------------
// Kernel 2: mean over p = 1..P-1 of num[p]/den[p], scaled by 1/(P-1).
// Double accumulation per thread, wave64 shuffle reduce, one atomic/block.
// ---------------------------------------------------------------------------
__global__ void __launch_bounds__(256)
reduce_kernel(const float* __restrict__ num,
              const float* __restrict__ den,
              float* __restrict__ out) {
    double local = 0.0;
    int stride = gridDim.x * blockDim.x;
    for (int p = 1 + blockIdx.x * blockDim.x + threadIdx.x; p < P_IDS; p += stride) {
        // division in fp32 to match reference semantics (incl. NaN on 0/0)
        local += (double)(num[p] / den[p]);
    }

    // wave64 butterfly reduce
    for (int off = 32; off > 0; off >>= 1)
        local += __shfl_down(local, off, 64);

    __shared__ double wave_sums[4];  // 256 threads / 64
    int lane = threadIdx.x & 63;
    int wid  = threadIdx.x >> 6;
    if (lane == 0) wave_sums[wid] = local;
    __syncthreads();

    if (threadIdx.x == 0) {
        double s = wave_sums[0] + wave_sums[1] + wave_sums[2] + wave_sums[3];
        atomicAdd(out, (float)(s / (double)(P_IDS - 1)));
    }
}

extern "C" void kernel_launch(void* const* d_in, const int* in_sizes, int n_in,
                              void* d_out, int out_size, void* d_ws, size_t ws_size,
                              hipStream_t stream) {
    // setup_inputs() order: beta, pred, particle_id, track_params, reconstructable
    const float*  beta  = (const float*)d_in[0];
    const float4* pred  = (const float4*)d_in[1];
    const int*    pid   = (const int*)d_in[2];
    const float4* track = (const float4*)d_in[3];
    const int*    recon = (const int*)d_in[4];
    float* out = (float*)d_out;

    float* num = (float*)d_ws;          // P_IDS floats
    float* den = num + P_IDS;           // P_IDS floats

    int n = in_sizes[0];  // N hits

    // ws and out are re-poisoned to 0xAA before every timed launch.
    hipMemsetAsync(d_ws, 0, 2 * P_IDS * sizeof(float), stream);
    hipMemsetAsync(d_out, 0, sizeof(float), stream);

    int block = 256;
    int grid = (n + block - 1) / block;
    scatter_kernel<<<grid, block, 0, stream>>>(beta, pred, pid, track, recon,
                                               num, den, n);
    reduce_kernel<<<128, 256, 0, stream>>>(num, den, out);
}